// Round 3
// baseline (34.998 us; speedup 1.0000x reference)
//
#include <hip/hip_runtime.h>

// Problem constants (from the reference): CNO=10000, PAD=10001, KS=10003.
#define CNO_C 10000
#define PAD_C 10001
#define KS_C  10003

// -------------------------------------------------------------------------
// mr==64 fast path: block-cooperative.
// Each 256-thread block owns 256 queries (QPB=256).
//   Phase A: thread i resolves query (qbase+i): picks table, loads starts/lens
//            once, writes a 16B descriptor {left, cnt_eff, tbl, 0} to LDS.
//   Phase B: 16 iterations; thread handles (query qq = tid>>4 + 16*i,
//            j4 = (tid&15)*4): 1 ds_read_b128 (broadcast) + 1 dwordx4 gather
//            + 2 dwordx4 stores. Metadata loads amortized 16x.
// -------------------------------------------------------------------------
__global__ __launch_bounds__(256) void akfi_block64(
    const int* __restrict__ qa,                                   // B x 3
    const int* __restrict__ o0, const int* __restrict__ s0, const int* __restrict__ l0,
    const int* __restrict__ o1, const int* __restrict__ s1, const int* __restrict__ l1,
    const int* __restrict__ op, const int* __restrict__ sp, const int* __restrict__ lp,
    int n0, int n1, int npred,
    int F, int B,
    int* __restrict__ out_idx,                                    // B x 64
    int* __restrict__ out_valid)                                  // B x 64 (0/1)
{
    __shared__ int4 desc[256];

    const int tid   = threadIdx.x;
    const int qbase = blockIdx.x << 8;

    // ---- Phase A: one thread per query resolves metadata ----
    {
        int q = qbase + tid;
        if (q < B) {
            int p  = qa[q * 3 + 0];
            int a0 = qa[q * 3 + 1];
            int a1 = qa[q * 3 + 2];

            bool is_c0 = (a0 <= CNO_C) && (a0 != PAD_C);
            bool is_c1 = (a1 <= CNO_C) && (a1 != PAD_C);
            bool both  = (!is_c0) && (!is_c1) && (p != PAD_C);

            // Reference select order: is_c0 -> t0; elif both_var -> pred; else t1.
            const int* starts; const int* lens;
            int key, nsz, tbl; bool isc;
            if (is_c0)      { starts = s0; lens = l0; key = p * KS_C + a0; nsz = n0;    isc = true;  tbl = 0; }
            else if (both)  { starts = sp; lens = lp; key = p;             nsz = npred; isc = true;  tbl = 1; }
            else            { starts = s1; lens = l1; key = p * KS_C + a1; nsz = n1;    isc = is_c1; tbl = 2; }

            int safe = min(max(key, 0), nsz - 1);
            int left = starts[safe];
            int cnt  = min(lens[safe], 64);
            int cnt_eff = isc ? cnt : 0;       // valid = (j < cnt) && isc

            desc[tid] = make_int4(left, cnt_eff, tbl, 0);
        }
    }
    __syncthreads();

    // ---- Phase B: 16 chunks per thread; fixed j4 per thread ----
    const int lq  = tid >> 4;                  // query sub-index stride base
    const int j4  = (tid & 15) << 2;           // fixed 4-elem chunk offset
    const int Fm1 = F - 1;

#pragma unroll 4
    for (int i = 0; i < 16; ++i) {
        int qq = lq + (i << 4);                // [0,256)
        int q  = qbase + qq;
        if (q >= B) continue;                  // tail block guard

        int4 d = desc[qq];                     // ds_read_b128, 16-lane broadcast
        const int* order = (d.z == 0) ? o0 : (d.z == 1) ? op : o1;

        int idx0 = d.x + j4;                   // reference clamps each to [0, F-1]
        int f0, f1, f2, f3;
        if (idx0 >= 0 && idx0 + 3 <= Fm1) {
            f0 = order[idx0];
            f1 = order[idx0 + 1];
            f2 = order[idx0 + 2];
            f3 = order[idx0 + 3];
        } else {
            f0 = order[min(max(idx0,     0), Fm1)];
            f1 = order[min(max(idx0 + 1, 0), Fm1)];
            f2 = order[min(max(idx0 + 2, 0), Fm1)];
            f3 = order[min(max(idx0 + 3, 0), Fm1)];
        }

        int cnt = d.y;
        int4 fv = make_int4(f0, f1, f2, f3);
        int4 vv = make_int4(j4 < cnt ? 1 : 0,
                            j4 + 1 < cnt ? 1 : 0,
                            j4 + 2 < cnt ? 1 : 0,
                            j4 + 3 < cnt ? 1 : 0);

        long long ob = ((long long)q << 6) + j4;   // 16B-aligned
        *reinterpret_cast<int4*>(out_idx + ob)   = fv;
        *reinterpret_cast<int4*>(out_valid + ob) = vv;
    }
}

// -------------------------------------------------------------------------
// Generic fallbacks (mr != 64).
// -------------------------------------------------------------------------
__global__ __launch_bounds__(256) void akfi_vec4(
    const int* __restrict__ qa,
    const int* __restrict__ o0, const int* __restrict__ s0, const int* __restrict__ l0,
    const int* __restrict__ o1, const int* __restrict__ s1, const int* __restrict__ l1,
    const int* __restrict__ op, const int* __restrict__ sp, const int* __restrict__ lp,
    int n0, int n1, int npred,
    int F, int B, int mr,
    int* __restrict__ out_idx,
    int* __restrict__ out_valid)
{
    long long t = (long long)blockIdx.x * blockDim.x + threadIdx.x;
    int per_q = mr >> 2;
    long long total = (long long)B * per_q;
    if (t >= total) return;

    int q = (int)(t / per_q), j4 = (int)(t % per_q) << 2;

    int p  = qa[q * 3 + 0];
    int a0 = qa[q * 3 + 1];
    int a1 = qa[q * 3 + 2];
    bool is_c0 = (a0 <= CNO_C) && (a0 != PAD_C);
    bool is_c1 = (a1 <= CNO_C) && (a1 != PAD_C);
    bool both  = (!is_c0) && (!is_c1) && (p != PAD_C);

    const int* order; const int* starts; const int* lens;
    int key, nsz; bool isc;
    if (is_c0)      { order = o0; starts = s0; lens = l0; key = p * KS_C + a0; nsz = n0;    isc = true;  }
    else if (both)  { order = op; starts = sp; lens = lp; key = p;             nsz = npred; isc = true;  }
    else            { order = o1; starts = s1; lens = l1; key = p * KS_C + a1; nsz = n1;    isc = is_c1; }

    int safe = min(max(key, 0), nsz - 1);
    int left = starts[safe];
    int cnt  = min(lens[safe], mr);
    if (!isc) cnt = 0;
    int Fm1 = F - 1;

    int idx0 = left + j4;
    int f0, f1, f2, f3;
    if (idx0 >= 0 && idx0 + 3 <= Fm1) {
        f0 = order[idx0]; f1 = order[idx0 + 1]; f2 = order[idx0 + 2]; f3 = order[idx0 + 3];
    } else {
        f0 = order[min(max(idx0,     0), Fm1)];
        f1 = order[min(max(idx0 + 1, 0), Fm1)];
        f2 = order[min(max(idx0 + 2, 0), Fm1)];
        f3 = order[min(max(idx0 + 3, 0), Fm1)];
    }

    int4 fv = make_int4(f0, f1, f2, f3);
    int4 vv = make_int4(j4 < cnt ? 1 : 0, j4 + 1 < cnt ? 1 : 0,
                        j4 + 2 < cnt ? 1 : 0, j4 + 3 < cnt ? 1 : 0);
    long long ob = (long long)q * mr + j4;
    *reinterpret_cast<int4*>(out_idx + ob)   = fv;
    *reinterpret_cast<int4*>(out_valid + ob) = vv;
}

__global__ __launch_bounds__(256) void akfi_scalar(
    const int* __restrict__ qa,
    const int* __restrict__ o0, const int* __restrict__ s0, const int* __restrict__ l0,
    const int* __restrict__ o1, const int* __restrict__ s1, const int* __restrict__ l1,
    const int* __restrict__ op, const int* __restrict__ sp, const int* __restrict__ lp,
    int n0, int n1, int npred,
    int F, int B, int mr,
    int* __restrict__ out_idx,
    int* __restrict__ out_valid)
{
    long long t = (long long)blockIdx.x * blockDim.x + threadIdx.x;
    long long total = (long long)B * (long long)mr;
    if (t >= total) return;
    int q = (int)(t / mr), j = (int)(t % mr);

    int p  = qa[q * 3 + 0];
    int a0 = qa[q * 3 + 1];
    int a1 = qa[q * 3 + 2];
    bool is_c0 = (a0 <= CNO_C) && (a0 != PAD_C);
    bool is_c1 = (a1 <= CNO_C) && (a1 != PAD_C);
    bool both  = (!is_c0) && (!is_c1) && (p != PAD_C);

    const int* order; const int* starts; const int* lens;
    int key, nsz; bool isc;
    if (is_c0)      { order = o0; starts = s0; lens = l0; key = p * KS_C + a0; nsz = n0;    isc = true;  }
    else if (both)  { order = op; starts = sp; lens = lp; key = p;             nsz = npred; isc = true;  }
    else            { order = o1; starts = s1; lens = l1; key = p * KS_C + a1; nsz = n1;    isc = is_c1; }

    int safe = min(max(key, 0), nsz - 1);
    int left = starts[safe];
    int cnt  = min(lens[safe], mr);
    int idx  = min(max(left + j, 0), F - 1);

    long long ob = (long long)q * mr + j;
    out_idx[ob]   = order[idx];
    out_valid[ob] = (isc && j < cnt) ? 1 : 0;
}

extern "C" void kernel_launch(void* const* d_in, const int* in_sizes, int n_in,
                              void* d_out, int out_size, void* d_ws, size_t ws_size,
                              hipStream_t stream) {
    const int* qa = (const int*)d_in[0];
    const int* o0 = (const int*)d_in[1];
    const int* s0 = (const int*)d_in[2];
    const int* l0 = (const int*)d_in[3];
    const int* o1 = (const int*)d_in[4];
    const int* s1 = (const int*)d_in[5];
    const int* l1 = (const int*)d_in[6];
    const int* op = (const int*)d_in[7];
    const int* sp = (const int*)d_in[8];
    const int* lp = (const int*)d_in[9];
    int B  = in_sizes[0] / 3;
    int F  = in_sizes[1];
    int n0 = in_sizes[2];
    int n1 = in_sizes[5];
    int npred = in_sizes[8];
    int mr = out_size / (2 * B);

    int* out_idx   = (int*)d_out;
    int* out_valid = (int*)d_out + (long long)B * mr;

    int block = 256;
    if (mr == 64) {
        int blocks = (B + 255) / 256;          // 256 queries per block
        akfi_block64<<<blocks, block, 0, stream>>>(
            qa, o0, s0, l0, o1, s1, l1, op, sp, lp,
            n0, n1, npred, F, B, out_idx, out_valid);
    } else if ((mr & 3) == 0) {
        long long total = (long long)B * (mr >> 2);
        int blocks = (int)((total + block - 1) / block);
        akfi_vec4<<<blocks, block, 0, stream>>>(
            qa, o0, s0, l0, o1, s1, l1, op, sp, lp,
            n0, n1, npred, F, B, mr, out_idx, out_valid);
    } else {
        long long total = (long long)B * (long long)mr;
        int blocks = (int)((total + block - 1) / block);
        akfi_scalar<<<blocks, block, 0, stream>>>(
            qa, o0, s0, l0, o1, s1, l1, op, sp, lp,
            n0, n1, npred, F, B, mr, out_idx, out_valid);
    }
}